// Round 2
// baseline (4284.735 us; speedup 1.0000x reference)
//
#include <hip/hip_runtime.h>
#include <math.h>

// Problem constants
#define NI 1152   // n_input
#define NO 32     // n_output
#define DI 32     // dim_input
#define DO 32     // dim_output
#define NBATCH 128

constexpr int IBLK = 36;                 // i's per workgroup
constexpr int NIB  = 32;                 // i-blocks  (32*36 = 1152)
constexpr int BBLK = 16;                 // batches per workgroup
constexpr int NBB  = NBATCH / BBLK;      // 8 batch-blocks
constexpr int LDS_FLOATS = 32 * 1024 + BBLK * 32 + BBLK * 32;  // Wt + xt + bl

// async 16B global -> LDS (linear dest: wave-uniform base + lane*16)
__device__ __forceinline__ void gll16(const float* g, float* l) {
  __builtin_amdgcn_global_load_lds(
      (const __attribute__((address_space(1))) void*)(const void*)g,
      (__attribute__((address_space(3))) void*)(void*)l, 16, 0, 0);
}

// Stage W[i] (swizzled source, linear LDS) and the 16x32 x-tile for i.
// LDS granule lin=(r*256+t) holds W src granule  (lin&~7) + ((lin&7) ^ ((lin>>5)&7)),
// i.e. storage (od,gc) holds k-group gc ^ ((od>>2)&7).  Per-thread this folds to
// src offset C(t) + r*256 granules.
__device__ __forceinline__ void stage_i(const float* __restrict__ xg,
                                        const float* __restrict__ Wg,
                                        float* Wt, float* xt,
                                        int i, int b0, int t) {
  const int w = t >> 6, l = t & 63;
  const int C = (t & ~7) + ((t & 7) ^ ((t >> 5) & 7));   // granule offset
  const float* src = Wg + (size_t)i * (NO * DO * DI) + (size_t)C * 4;
  float* dst = Wt + w * 256;
#pragma unroll
  for (int r = 0; r < 32; ++r)
    gll16(src + (size_t)r * 1024, dst + r * 1024);
  if (w < 2) {
    const int b  = w * 8 + (l >> 3);
    const int k4 = l & 7;
    gll16(xg + (size_t)(b0 + b) * (NI * DI) + (size_t)i * DI + k4 * 4,
          xt + w * 256);
  }
}

// Pass kernel: one routing iteration.
//  IT==0: c = 1/32 uniform, accumulate s0 partials.
//  IT==1: blog = sum_d x_hat*v0 ; write blog to bbuf ; softmax ; s1 partials.
//  IT==2: blog = bbuf + sum_d x_hat*v1 ; softmax ; s2 partials.
// v is reconstructed as f * s_in (squash factor f in fsc[0]).
template<int IT>
__global__ __launch_bounds__(256, 1)
void caps_pass(const float* __restrict__ xg, const float* __restrict__ Wg,
               float* __restrict__ spart, const float* __restrict__ s_in,
               const float* __restrict__ fsc, float* __restrict__ bbuf)
{
  extern __shared__ float lds[];
  float* Wt = lds;                    // [od=1024][k=32], k-group swizzled (128 KB)
  float* xt = lds + 32 * 1024;        // [b=16][k=32]
  float* bl = xt + BBLK * 32;         // [b=16][o=32]

  const int t  = threadIdx.x;
  const int ib = blockIdx.x;          // 0..31
  const int b0 = blockIdx.y * BBLK;   // batch base
  const int o  = t >> 3;              // 0..31
  const int d0 = (t & 7) * 4;         // d-quad base
  const int q  = t & 7;

  // per-thread W read pointers: row od=4t, column group g stored at 4*(g^q)
  const float* pW[8];
#pragma unroll
  for (int g = 0; g < 8; ++g) pW[g] = Wt + t * 128 + 4 * (g ^ q);

  float sreg[BBLK][4];
#pragma unroll
  for (int b = 0; b < BBLK; ++b)
#pragma unroll
    for (int j = 0; j < 4; ++j) sreg[b][j] = 0.f;

  float f = 0.f;
  if constexpr (IT > 0) f = fsc[0];

  // prologue: stage first tile
  stage_i(xg, Wg, Wt, xt, ib * IBLK, b0, t);
  asm volatile("s_waitcnt vmcnt(0)" ::: "memory");
  __syncthreads();

  for (int ii = 0; ii < IBLK; ++ii) {
    const int i = ib * IBLK + ii;

    // ---- phase A: acc[b][j] = sum_k W[i,o,d0+j,k] * x[b,i,k] ----
    float acc[BBLK][4];
#pragma unroll
    for (int b = 0; b < BBLK; ++b)
#pragma unroll
      for (int j = 0; j < 4; ++j) acc[b][j] = 0.f;

#pragma unroll
    for (int g = 0; g < 8; ++g) {
      const float4 w0 = *(const float4*)(pW[g]);
      const float4 w1 = *(const float4*)(pW[g] + 32);
      const float4 w2 = *(const float4*)(pW[g] + 64);
      const float4 w3 = *(const float4*)(pW[g] + 96);
#pragma unroll
      for (int b = 0; b < BBLK; ++b) {
        const float4 xv = *(const float4*)(xt + b * 32 + g * 4);
        acc[b][0] = fmaf(w0.x, xv.x, acc[b][0]);
        acc[b][0] = fmaf(w0.y, xv.y, acc[b][0]);
        acc[b][0] = fmaf(w0.z, xv.z, acc[b][0]);
        acc[b][0] = fmaf(w0.w, xv.w, acc[b][0]);
        acc[b][1] = fmaf(w1.x, xv.x, acc[b][1]);
        acc[b][1] = fmaf(w1.y, xv.y, acc[b][1]);
        acc[b][1] = fmaf(w1.z, xv.z, acc[b][1]);
        acc[b][1] = fmaf(w1.w, xv.w, acc[b][1]);
        acc[b][2] = fmaf(w2.x, xv.x, acc[b][2]);
        acc[b][2] = fmaf(w2.y, xv.y, acc[b][2]);
        acc[b][2] = fmaf(w2.z, xv.z, acc[b][2]);
        acc[b][2] = fmaf(w2.w, xv.w, acc[b][2]);
        acc[b][3] = fmaf(w3.x, xv.x, acc[b][3]);
        acc[b][3] = fmaf(w3.y, xv.y, acc[b][3]);
        acc[b][3] = fmaf(w3.z, xv.z, acc[b][3]);
        acc[b][3] = fmaf(w3.w, xv.w, acc[b][3]);
      }
    }
    __syncthreads();   // all waves done reading Wt/xt

    // ---- phase B: async prefetch of next tile into the same buffers ----
    if (ii + 1 < IBLK) stage_i(xg, Wg, Wt, xt, i + 1, b0, t);

    // ---- phase C: routing ----
    if constexpr (IT == 0) {
#pragma unroll
      for (int b = 0; b < BBLK; ++b)
#pragma unroll
        for (int j = 0; j < 4; ++j) sreg[b][j] += 0.03125f * acc[b][j];
    } else {
      // b-logit update: sum_d x_hat[o,d] * v[b,o,d], v = f*s_in
      float bup[BBLK];
#pragma unroll
      for (int b = 0; b < BBLK; ++b) {
        const float4 sv = *(const float4*)(
            s_in + (size_t)(b0 + b) * 1024 + o * 32 + d0);
        bup[b] = f * (acc[b][0] * sv.x + acc[b][1] * sv.y +
                      acc[b][2] * sv.z + acc[b][3] * sv.w);
      }
#pragma unroll
      for (int m = 1; m < 8; m <<= 1)
#pragma unroll
        for (int b = 0; b < BBLK; ++b) bup[b] += __shfl_xor(bup[b], m);

      if (q == 0) {
#pragma unroll
        for (int b = 0; b < BBLK; ++b) {
          float bp = 0.f;
          if constexpr (IT == 2)
            bp = bbuf[(size_t)(b0 + b) * (NI * NO) + (size_t)i * NO + o];
          bl[b * 32 + o] = bup[b] + bp;
        }
      }
      __syncthreads();

      // softmax over o (32 lanes per row)
      const int o2 = t & 31, bloc = t >> 5;
      float cv[2];
#pragma unroll
      for (int rep = 0; rep < 2; ++rep) {
        const int b = rep * 8 + bloc;
        const float lg = bl[b * 32 + o2];
        if constexpr (IT == 1)
          bbuf[(size_t)(b0 + b) * (NI * NO) + (size_t)i * NO + o2] = lg;
        float mx = lg;
#pragma unroll
        for (int m = 1; m < 32; m <<= 1) mx = fmaxf(mx, __shfl_xor(mx, m));
        const float e = __expf(lg - mx);
        float sm = e;
#pragma unroll
        for (int m = 1; m < 32; m <<= 1) sm += __shfl_xor(sm, m);
        cv[rep] = e / sm;
      }
      __syncthreads();
#pragma unroll
      for (int rep = 0; rep < 2; ++rep) bl[(rep * 8 + bloc) * 32 + o2] = cv[rep];
      __syncthreads();

      // s partial accumulate
#pragma unroll
      for (int b = 0; b < BBLK; ++b) {
        const float c = bl[b * 32 + o];
#pragma unroll
        for (int j = 0; j < 4; ++j) sreg[b][j] += c * acc[b][j];
      }
    }

    // wait for prefetched tile, publish
    asm volatile("s_waitcnt vmcnt(0)" ::: "memory");
    __syncthreads();
  }

  // ---- flush s partials: spart[ib][b][o*32+d] ----
#pragma unroll
  for (int b = 0; b < BBLK; ++b) {
    float4 v4;
    v4.x = sreg[b][0]; v4.y = sreg[b][1]; v4.z = sreg[b][2]; v4.w = sreg[b][3];
    *reinterpret_cast<float4*>(
        spart + (size_t)ib * (NBATCH * 1024) + (size_t)(b0 + b) * 1024 + o * 32 + d0) = v4;
  }
}

// Reduce partials over i-blocks, emit s and per-block sum of squares.
__global__ __launch_bounds__(256)
void caps_red(const float* __restrict__ spart, float* __restrict__ s,
              float* __restrict__ part)
{
  const int t = threadIdx.x;
  const size_t e = (size_t)blockIdx.x * 256 + t;
  float a = 0.f;
#pragma unroll
  for (int ib = 0; ib < NIB; ++ib) a += spart[(size_t)ib * (NBATCH * 1024) + e];
  s[e] = a;
  float qv = a * a;
#pragma unroll
  for (int m = 1; m < 64; m <<= 1) qv += __shfl_xor(qv, m);
  __shared__ float red[4];
  if ((t & 63) == 0) red[t >> 6] = qv;
  __syncthreads();
  if (t == 0) part[blockIdx.x] = red[0] + red[1] + red[2] + red[3];
}

// Global norm -> squash factor f = n / (1 + n^2)
__global__ __launch_bounds__(256)
void caps_norm(const float* __restrict__ part, float* __restrict__ fsc)
{
  const int t = threadIdx.x;
  float qv = part[t] + part[t + 256];
#pragma unroll
  for (int m = 1; m < 64; m <<= 1) qv += __shfl_xor(qv, m);
  __shared__ float red[4];
  if ((t & 63) == 0) red[t >> 6] = qv;
  __syncthreads();
  if (t == 0) {
    const float S = red[0] + red[1] + red[2] + red[3];
    fsc[0] = sqrtf(S) / (1.f + S);
  }
}

__global__ __launch_bounds__(256)
void caps_out(const float* __restrict__ s, const float* __restrict__ fsc,
              float* __restrict__ out)
{
  const size_t e = (size_t)blockIdx.x * 256 + threadIdx.x;
  out[e] = s[e] * fsc[0];
}

extern "C" void kernel_launch(void* const* d_in, const int* in_sizes, int n_in,
                              void* d_out, int out_size, void* d_ws, size_t ws_size,
                              hipStream_t stream)
{
  const float* xg = (const float*)d_in[0];
  const float* Wg = (const float*)d_in[1];
  float* out = (float*)d_out;

  // workspace layout (floats): spart[32][131072] | s[131072] | part[512] | f[1] | bbuf
  float* wsf   = (float*)d_ws;
  float* spart = wsf;
  float* s     = spart + (size_t)NIB * NBATCH * 1024;
  float* part  = s + (size_t)NBATCH * 1024;
  float* fsc   = part + 512;
  float* bbuf  = fsc + 1;

  const int ldsB = LDS_FLOATS * 4;   // 132 KB dynamic LDS (proven to launch in r1)
  hipFuncSetAttribute(reinterpret_cast<const void*>(&caps_pass<0>),
                      hipFuncAttributeMaxDynamicSharedMemorySize, ldsB);
  hipFuncSetAttribute(reinterpret_cast<const void*>(&caps_pass<1>),
                      hipFuncAttributeMaxDynamicSharedMemorySize, ldsB);
  hipFuncSetAttribute(reinterpret_cast<const void*>(&caps_pass<2>),
                      hipFuncAttributeMaxDynamicSharedMemorySize, ldsB);

  dim3 pg(NIB, NBB);   // (32, 8) = 256 workgroups, 1 per CU

  caps_pass<0><<<pg, 256, ldsB, stream>>>(xg, Wg, spart, s, fsc, bbuf);
  caps_red <<<512, 256, 0, stream>>>(spart, s, part);
  caps_norm<<<1,   256, 0, stream>>>(part, fsc);

  caps_pass<1><<<pg, 256, ldsB, stream>>>(xg, Wg, spart, s, fsc, bbuf);
  caps_red <<<512, 256, 0, stream>>>(spart, s, part);
  caps_norm<<<1,   256, 0, stream>>>(part, fsc);

  caps_pass<2><<<pg, 256, ldsB, stream>>>(xg, Wg, spart, s, fsc, bbuf);
  caps_red <<<512, 256, 0, stream>>>(spart, s, part);
  caps_norm<<<1,   256, 0, stream>>>(part, fsc);

  caps_out <<<512, 256, 0, stream>>>(s, fsc, out);
}

// Round 3
// 1076.972 us; speedup vs baseline: 3.9785x; 3.9785x over previous
//
#include <hip/hip_runtime.h>
#include <math.h>

// Problem constants
#define NI 1152   // n_input
#define NO 32     // n_output
#define DI 32     // dim_input
#define DO 32     // dim_output
#define NBATCH 128

constexpr int IBLK = 36;                 // i's per workgroup
constexpr int NIB  = 32;                 // i-blocks  (32*36 = 1152)
constexpr int BBLK = 8;                  // batches per workgroup (8 -> no spills)
constexpr int NBB  = NBATCH / BBLK;      // 16 batch-blocks
constexpr int LDS_FLOATS = 32 * 1024 + BBLK * 32 + BBLK * 32;  // Wt + xt + bl

// async 16B global -> LDS (linear dest: wave-uniform base + lane*16)
__device__ __forceinline__ void gll16(const float* g, float* l) {
  __builtin_amdgcn_global_load_lds(
      (const __attribute__((address_space(1))) void*)(const void*)g,
      (__attribute__((address_space(3))) void*)(void*)l, 16, 0, 0);
}

// Stage W[i] (swizzled source, linear LDS) and the 8x32 x-tile for i.
// LDS granule lin=(r*256+t) holds W src granule (lin&~7) + ((lin&7) ^ ((lin>>5)&7)),
// i.e. storage (od,gc) holds k-group gc ^ ((od>>2)&7).
__device__ __forceinline__ void stage_i(const float* __restrict__ xg,
                                        const float* __restrict__ Wg,
                                        float* Wt, float* xt,
                                        int i, int b0, int t) {
  const int w = t >> 6, l = t & 63;
  const int C = (t & ~7) + ((t & 7) ^ ((t >> 5) & 7));   // granule offset
  const float* src = Wg + (size_t)i * (NO * DO * DI) + (size_t)C * 4;
  float* dst = Wt + w * 256;
#pragma unroll
  for (int r = 0; r < 32; ++r)
    gll16(src + (size_t)r * 1024, dst + r * 1024);
  if (w == 0) {   // x tile: 8 b x 32 k = 64 granules, one wave
    const int b  = l >> 3;
    const int k4 = l & 7;
    gll16(xg + (size_t)(b0 + b) * (NI * DI) + (size_t)i * DI + k4 * 4, xt);
  }
}

// Pass kernel: one routing iteration.
//  IT==0: c = 1/32 uniform, accumulate s0 partials.
//  IT==1: blog = sum_d x_hat*v0 ; write blog to bbuf ; softmax ; s1 partials.
//  IT==2: blog = bbuf + sum_d x_hat*v1 ; softmax ; s2 partials.
// v is reconstructed as f * s_in (squash factor f in fsc[0]).
template<int IT>
__global__ __launch_bounds__(256, 1)
void caps_pass(const float* __restrict__ xg, const float* __restrict__ Wg,
               float* __restrict__ spart, const float* __restrict__ s_in,
               const float* __restrict__ fsc, float* __restrict__ bbuf)
{
  extern __shared__ float lds[];
  float* Wt = lds;                    // [od=1024][k=32], k-group swizzled (128 KB)
  float* xt = lds + 32 * 1024;        // [b=8][k=32]
  float* bl = xt + BBLK * 32;         // [b=8][o=32]

  const int t  = threadIdx.x;
  const int ib = blockIdx.x;          // 0..31
  const int b0 = blockIdx.y * BBLK;   // batch base
  const int o  = t >> 3;              // 0..31
  const int d0 = (t & 7) * 4;         // d-quad base
  const int q  = t & 7;

  // per-thread W read pointers: rows od=4t.., column group g stored at 4*(g^q)
  const float* pW[8];
#pragma unroll
  for (int g = 0; g < 8; ++g) pW[g] = Wt + t * 128 + 4 * (g ^ q);

  float sreg[BBLK][4];
#pragma unroll
  for (int b = 0; b < BBLK; ++b)
#pragma unroll
    for (int j = 0; j < 4; ++j) sreg[b][j] = 0.f;

  float f = 0.f;
  if constexpr (IT > 0) f = fsc[0];

  // prologue: stage first tile
  stage_i(xg, Wg, Wt, xt, ib * IBLK, b0, t);
  asm volatile("s_waitcnt vmcnt(0)" ::: "memory");
  __syncthreads();

  for (int ii = 0; ii < IBLK; ++ii) {
    const int i = ib * IBLK + ii;

    // ---- phase A: acc[b][j] = sum_k W[i,o,d0+j,k] * x[b,i,k] ----
    float acc[BBLK][4];
#pragma unroll
    for (int b = 0; b < BBLK; ++b)
#pragma unroll
      for (int j = 0; j < 4; ++j) acc[b][j] = 0.f;

#pragma unroll
    for (int g = 0; g < 8; ++g) {
      const float4 w0 = *(const float4*)(pW[g]);
      const float4 w1 = *(const float4*)(pW[g] + 32);
      const float4 w2 = *(const float4*)(pW[g] + 64);
      const float4 w3 = *(const float4*)(pW[g] + 96);
#pragma unroll
      for (int b = 0; b < BBLK; ++b) {
        const float4 xv = *(const float4*)(xt + b * 32 + g * 4);
        acc[b][0] = fmaf(w0.x, xv.x, acc[b][0]);
        acc[b][0] = fmaf(w0.y, xv.y, acc[b][0]);
        acc[b][0] = fmaf(w0.z, xv.z, acc[b][0]);
        acc[b][0] = fmaf(w0.w, xv.w, acc[b][0]);
        acc[b][1] = fmaf(w1.x, xv.x, acc[b][1]);
        acc[b][1] = fmaf(w1.y, xv.y, acc[b][1]);
        acc[b][1] = fmaf(w1.z, xv.z, acc[b][1]);
        acc[b][1] = fmaf(w1.w, xv.w, acc[b][1]);
        acc[b][2] = fmaf(w2.x, xv.x, acc[b][2]);
        acc[b][2] = fmaf(w2.y, xv.y, acc[b][2]);
        acc[b][2] = fmaf(w2.z, xv.z, acc[b][2]);
        acc[b][2] = fmaf(w2.w, xv.w, acc[b][2]);
        acc[b][3] = fmaf(w3.x, xv.x, acc[b][3]);
        acc[b][3] = fmaf(w3.y, xv.y, acc[b][3]);
        acc[b][3] = fmaf(w3.z, xv.z, acc[b][3]);
        acc[b][3] = fmaf(w3.w, xv.w, acc[b][3]);
      }
    }
    __syncthreads();   // all waves done reading Wt/xt

    // ---- phase B: async prefetch of next tile into the same buffers ----
    if (ii + 1 < IBLK) stage_i(xg, Wg, Wt, xt, i + 1, b0, t);

    // ---- phase C: routing ----
    if constexpr (IT == 0) {
#pragma unroll
      for (int b = 0; b < BBLK; ++b)
#pragma unroll
        for (int j = 0; j < 4; ++j) sreg[b][j] += 0.03125f * acc[b][j];
    } else {
      // b-logit update: sum_d x_hat[o,d] * v[b,o,d], v = f*s_in
      float bup[BBLK];
#pragma unroll
      for (int b = 0; b < BBLK; ++b) {
        const float4 sv = *(const float4*)(
            s_in + (size_t)(b0 + b) * 1024 + o * 32 + d0);
        bup[b] = f * (acc[b][0] * sv.x + acc[b][1] * sv.y +
                      acc[b][2] * sv.z + acc[b][3] * sv.w);
      }
#pragma unroll
      for (int m = 1; m < 8; m <<= 1)
#pragma unroll
        for (int b = 0; b < BBLK; ++b) bup[b] += __shfl_xor(bup[b], m);

      if (q == 0) {
#pragma unroll
        for (int b = 0; b < BBLK; ++b) {
          float bp = 0.f;
          if constexpr (IT == 2)
            bp = bbuf[(size_t)(b0 + b) * (NI * NO) + (size_t)i * NO + o];
          bl[b * 32 + o] = bup[b] + bp;
        }
      }
      __syncthreads();

      // softmax over o: 8 rows x 32 lanes (256 threads exactly)
      {
        const int o2 = t & 31, bloc = t >> 5;
        const float lg = bl[bloc * 32 + o2];
        if constexpr (IT == 1)
          bbuf[(size_t)(b0 + bloc) * (NI * NO) + (size_t)i * NO + o2] = lg;
        float mx = lg;
#pragma unroll
        for (int m = 1; m < 32; m <<= 1) mx = fmaxf(mx, __shfl_xor(mx, m));
        const float e = __expf(lg - mx);
        float sm = e;
#pragma unroll
        for (int m = 1; m < 32; m <<= 1) sm += __shfl_xor(sm, m);
        const float cv = e / sm;
        __syncthreads();
        bl[bloc * 32 + o2] = cv;
        __syncthreads();
      }

      // s partial accumulate
#pragma unroll
      for (int b = 0; b < BBLK; ++b) {
        const float c = bl[b * 32 + o];
#pragma unroll
        for (int j = 0; j < 4; ++j) sreg[b][j] += c * acc[b][j];
      }
    }

    // wait for prefetched tile, publish
    asm volatile("s_waitcnt vmcnt(0)" ::: "memory");
    __syncthreads();
  }

  // ---- flush s partials: spart[ib][b][o*32+d] ----
#pragma unroll
  for (int b = 0; b < BBLK; ++b) {
    float4 v4;
    v4.x = sreg[b][0]; v4.y = sreg[b][1]; v4.z = sreg[b][2]; v4.w = sreg[b][3];
    *reinterpret_cast<float4*>(
        spart + (size_t)ib * (NBATCH * 1024) + (size_t)(b0 + b) * 1024 + o * 32 + d0) = v4;
  }
}

// Reduce partials over i-blocks, emit s and per-block sum of squares.
__global__ __launch_bounds__(256)
void caps_red(const float* __restrict__ spart, float* __restrict__ s,
              float* __restrict__ part)
{
  const int t = threadIdx.x;
  const size_t e = (size_t)blockIdx.x * 256 + t;
  float a = 0.f;
#pragma unroll
  for (int ib = 0; ib < NIB; ++ib) a += spart[(size_t)ib * (NBATCH * 1024) + e];
  s[e] = a;
  float qv = a * a;
#pragma unroll
  for (int m = 1; m < 64; m <<= 1) qv += __shfl_xor(qv, m);
  __shared__ float red[4];
  if ((t & 63) == 0) red[t >> 6] = qv;
  __syncthreads();
  if (t == 0) part[blockIdx.x] = red[0] + red[1] + red[2] + red[3];
}

// Global norm -> squash factor f = n / (1 + n^2)
__global__ __launch_bounds__(256)
void caps_norm(const float* __restrict__ part, float* __restrict__ fsc)
{
  const int t = threadIdx.x;
  float qv = part[t] + part[t + 256];
#pragma unroll
  for (int m = 1; m < 64; m <<= 1) qv += __shfl_xor(qv, m);
  __shared__ float red[4];
  if ((t & 63) == 0) red[t >> 6] = qv;
  __syncthreads();
  if (t == 0) {
    const float S = red[0] + red[1] + red[2] + red[3];
    fsc[0] = sqrtf(S) / (1.f + S);
  }
}

__global__ __launch_bounds__(256)
void caps_out(const float* __restrict__ s, const float* __restrict__ fsc,
              float* __restrict__ out)
{
  const size_t e = (size_t)blockIdx.x * 256 + threadIdx.x;
  out[e] = s[e] * fsc[0];
}

extern "C" void kernel_launch(void* const* d_in, const int* in_sizes, int n_in,
                              void* d_out, int out_size, void* d_ws, size_t ws_size,
                              hipStream_t stream)
{
  const float* xg = (const float*)d_in[0];
  const float* Wg = (const float*)d_in[1];
  float* out = (float*)d_out;

  // workspace layout (floats): spart[32][131072] | s[131072] | part[512] | f[1] | bbuf
  float* wsf   = (float*)d_ws;
  float* spart = wsf;
  float* s     = spart + (size_t)NIB * NBATCH * 1024;
  float* part  = s + (size_t)NBATCH * 1024;
  float* fsc   = part + 512;
  float* bbuf  = fsc + 1;

  const int ldsB = LDS_FLOATS * 4;   // 130 KB dynamic LDS
  hipFuncSetAttribute(reinterpret_cast<const void*>(&caps_pass<0>),
                      hipFuncAttributeMaxDynamicSharedMemorySize, ldsB);
  hipFuncSetAttribute(reinterpret_cast<const void*>(&caps_pass<1>),
                      hipFuncAttributeMaxDynamicSharedMemorySize, ldsB);
  hipFuncSetAttribute(reinterpret_cast<const void*>(&caps_pass<2>),
                      hipFuncAttributeMaxDynamicSharedMemorySize, ldsB);

  dim3 pg(NIB, NBB);   // (32, 16) = 512 workgroups

  caps_pass<0><<<pg, 256, ldsB, stream>>>(xg, Wg, spart, s, fsc, bbuf);
  caps_red <<<512, 256, 0, stream>>>(spart, s, part);
  caps_norm<<<1,   256, 0, stream>>>(part, fsc);

  caps_pass<1><<<pg, 256, ldsB, stream>>>(xg, Wg, spart, s, fsc, bbuf);
  caps_red <<<512, 256, 0, stream>>>(spart, s, part);
  caps_norm<<<1,   256, 0, stream>>>(part, fsc);

  caps_pass<2><<<pg, 256, ldsB, stream>>>(xg, Wg, spart, s, fsc, bbuf);
  caps_red <<<512, 256, 0, stream>>>(spart, s, part);
  caps_norm<<<1,   256, 0, stream>>>(part, fsc);

  caps_out <<<512, 256, 0, stream>>>(s, fsc, out);
}

// Round 6
// 389.555 us; speedup vs baseline: 10.9991x; 2.7646x over previous
//
#include <hip/hip_runtime.h>
#include <math.h>

// Problem constants
#define NI 1152
#define NO 32
#define DI 32
#define DO 32
#define NBATCH 128

constexpr int IBLK = 36;                 // i's per block
constexpr int NIB  = 32;                 // i-blocks
constexpr int BBLK = 16;                 // batches per block
constexpr int NBB  = NBATCH / BBLK;      // 8
// LDS: Wt fp32 [1024 od][32 k] (16B-granule col-swizzled) + bl [16][32]
constexpr int LDS_FLOATS = 32 * 1024 + 16 * 32;

typedef __attribute__((ext_vector_type(8))) short short8v;
typedef __attribute__((ext_vector_type(4))) float f32x4;
typedef __attribute__((ext_vector_type(2))) float f32x2;

__device__ __forceinline__ void gll16(const float* g, float* l) {
  __builtin_amdgcn_global_load_lds(
      (const __attribute__((address_space(1))) void*)(const void*)g,
      (__attribute__((address_space(3))) void*)(void*)l, 16, 0, 0);
}

#define WAITV(n) do { asm volatile("s_waitcnt vmcnt(" #n ")" ::: "memory"); \
  __builtin_amdgcn_sched_barrier(0); } while (0)
#define LGKM0() do { asm volatile("s_waitcnt lgkmcnt(0)" ::: "memory"); \
  __builtin_amdgcn_sched_barrier(0); } while (0)
#define BARLDS() do { asm volatile("s_waitcnt lgkmcnt(0)" ::: "memory"); \
  __builtin_amdgcn_sched_barrier(0); __builtin_amdgcn_s_barrier(); } while (0)

// 3-way truncation split: w = hi + mid + lo (bf16 each), residual <= 2^-23|w|.
struct S3 { short hi, mi, lo; };
__device__ __forceinline__ S3 split3(float w) {
  S3 r;
  const unsigned u = __float_as_uint(w);
  r.hi = (short)(u >> 16);
  const float r1 = w - __uint_as_float(u & 0xFFFF0000u);
  const unsigned r1u = __float_as_uint(r1);
  r.mi = (short)(r1u >> 16);
  const float r2 = r1 - __uint_as_float(r1u & 0xFFFF0000u);
  r.lo = (short)(__float_as_uint(r2) >> 16);
  return r;
}

// Stage one 64-row half of wave w's private W slab (8 gll16 per lane).
// Storage swizzle: 16B granule (od, q) holds source granule (q ^ (od&7)).
__device__ __forceinline__ void stage_w_half(const float* __restrict__ Wg,
                                             float* __restrict__ Wt,
                                             int i, int h, int w, size_t wsrc_lane) {
  const float* sb = Wg + (size_t)i * 32768 + wsrc_lane + (size_t)h * 2048;
  float* db = Wt + (size_t)(w * 1024 + h * 512) * 4;
#pragma unroll
  for (int r = 0; r < 8; ++r)
    gll16(sb + r * 256, db + r * 256);
}

// One routing iteration.
//  IT==0: c = 1/32, accumulate s0 partials.
//  IT==1: logits = sum_d x_hat*v0 ; write to bbuf ; softmax ; s1 partials.
//  IT==2: logits = bbuf + sum_d x_hat*v1 ; softmax ; s2 partials.
template<int IT>
__global__ __launch_bounds__(512, 2)
void caps_pass(const float* __restrict__ xg, const float* __restrict__ Wg,
               float* __restrict__ spart, const float* __restrict__ s_in,
               const float* __restrict__ fsc, float* __restrict__ bbuf)
{
  extern __shared__ float lds[];
  float* Wt = lds;                    // 128 KB
  float* bl = lds + 32 * 1024;        // 2 KB  [b=16][o=32]

  const int t = threadIdx.x, w = t >> 6, l = t & 63;
  const int ib = blockIdx.x, bb = blockIdx.y, b0 = bb * BBLK;

  // per-lane staging source offset (granules), constant over (i,h,r)
  const size_t wsrc_lane = (size_t)(w * 128 + (l >> 3)) * 32
                         + (size_t)(((l & 7) ^ (l >> 3)) * 4);

  // per-lane swizzled A-read column offsets (floats)
  int colf[4];
#pragma unroll
  for (int s = 0; s < 4; ++s)
    colf[s] = ((((l >> 4) * 2 + (s >> 1)) ^ (l & 7)) * 4) + (s & 1) * 2;

  // x fragment source: x[b = l&15][k = (l>>4)*8 + e], 8 contiguous floats
  const float* xbase = xg + (size_t)(b0 + (l & 15)) * (NI * DI) + (l >> 4) * 8;

  // v fragments (IT>0): v = f * s_in, fragment-natural flat layout
  f32x4 vfrag[8];
  if constexpr (IT > 0) {
    const float f = fsc[0];
    const float* vp = s_in + (size_t)bb * 16384 + w * 2048 + l * 4;
#pragma unroll
    for (int tl = 0; tl < 8; ++tl) {
      f32x4 sv = *(const f32x4*)(vp + tl * 256);
      vfrag[tl] = sv * f;
    }
  }
  WAITV(0);   // start the gll queue from a clean counter

  f32x4 sreg[8];
#pragma unroll
  for (int tl = 0; tl < 8; ++tl) sreg[tl] = (f32x4){0.f, 0.f, 0.f, 0.f};

  const int i0 = ib * IBLK;
  // prologue queue = [H0(8), X(2 reg dwordx4), H1(8)]
  stage_w_half(Wg, Wt, i0, 0, w, wsrc_lane);
  f32x4 xa = *(const f32x4*)(xbase + (size_t)i0 * DI);
  f32x4 xb = *(const f32x4*)(xbase + (size_t)i0 * DI + 4);
  stage_w_half(Wg, Wt, i0, 1, w, wsrc_lane);

  for (int ii = 0; ii < IBLK; ++ii) {
    const int i = i0 + ii;
    const int inext = i0 + ((ii + 1 < IBLK) ? ii + 1 : ii);  // uniform counts

    f32x4 acc[8];
#pragma unroll
    for (int tl = 0; tl < 8; ++tl) acc[tl] = (f32x4){0.f, 0.f, 0.f, 0.f};

    short8v xhi, xmi, xlo;
    f32x4 xna, xnb;

#pragma unroll
    for (int h = 0; h < 2; ++h) {
      // read this half's W fragments into registers
      f32x2 wf[4][4];
      if (h == 0) {
        WAITV(8);    // H0(i), X(i) retired (H1(i) may be in flight)
#pragma unroll
        for (int e = 0; e < 4; ++e) {
          S3 sa = split3(xa[e]);
          xhi[e] = sa.hi; xmi[e] = sa.mi; xlo[e] = sa.lo;
          S3 sb2 = split3(xb[e]);
          xhi[4 + e] = sb2.hi; xmi[4 + e] = sb2.mi; xlo[4 + e] = sb2.lo;
        }
      } else {
        WAITV(10);   // H1(i) retired (H0(i+1)+X(i+1) in flight)
      }
#pragma unroll
      for (int tl = 0; tl < 4; ++tl) {
        const float* rp = Wt + (size_t)(w * 128 + (h * 4 + tl) * 16 + (l & 15)) * 32;
#pragma unroll
        for (int s = 0; s < 4; ++s) wf[tl][s] = *(const f32x2*)(rp + colf[s]);
      }
      LGKM0();       // all ds_reads complete before overwriting prefetch

      if (h == 0) {
        stage_w_half(Wg, Wt, inext, 0, w, wsrc_lane);
        xna = *(const f32x4*)(xbase + (size_t)inext * DI);
        xnb = *(const f32x4*)(xbase + (size_t)inext * DI + 4);
      } else {
        stage_w_half(Wg, Wt, inext, 1, w, wsrc_lane);
      }

      // split W fragments and run 6-product MFMA per tile
#pragma unroll
      for (int tl = 0; tl < 4; ++tl) {
        const int tloc = h * 4 + tl;
        short8v whi, wmi, wlo;
#pragma unroll
        for (int s = 0; s < 4; ++s) {
          S3 s0 = split3(wf[tl][s].x);
          whi[2 * s] = s0.hi; wmi[2 * s] = s0.mi; wlo[2 * s] = s0.lo;
          S3 s1 = split3(wf[tl][s].y);
          whi[2 * s + 1] = s1.hi; wmi[2 * s + 1] = s1.mi; wlo[2 * s + 1] = s1.lo;
        }
        f32x4 a = acc[tloc];
        a = __builtin_amdgcn_mfma_f32_16x16x32_bf16(whi, xhi, a, 0, 0, 0);
        a = __builtin_amdgcn_mfma_f32_16x16x32_bf16(whi, xmi, a, 0, 0, 0);
        a = __builtin_amdgcn_mfma_f32_16x16x32_bf16(wmi, xhi, a, 0, 0, 0);
        a = __builtin_amdgcn_mfma_f32_16x16x32_bf16(whi, xlo, a, 0, 0, 0);
        a = __builtin_amdgcn_mfma_f32_16x16x32_bf16(wlo, xhi, a, 0, 0, 0);
        a = __builtin_amdgcn_mfma_f32_16x16x32_bf16(wmi, xmi, a, 0, 0, 0);
        acc[tloc] = a;
      }
    }
    xa = xna; xb = xnb;

    // ---- routing ----
    if constexpr (IT == 0) {
#pragma unroll
      for (int tl = 0; tl < 8; ++tl) sreg[tl] += acc[tl] * 0.03125f;
    } else {
      // logit: lane holds x_hat rows od = w*128 + tloc*16 + (l>>4)*4 + r, col b = l&15
      float bup[4];
#pragma unroll
      for (int j = 0; j < 4; ++j) {
        f32x4 p = acc[2 * j] * vfrag[2 * j] + acc[2 * j + 1] * vfrag[2 * j + 1];
        float v = p[0] + p[1] + p[2] + p[3];
        v += __shfl_xor(v, 16);
        v += __shfl_xor(v, 32);
        bup[j] = v;
      }
      if (l < 16) {
#pragma unroll
        for (int j = 0; j < 4; ++j) bl[l * 32 + w * 4 + j] = bup[j];
      }
      BARLDS();

      {  // softmax over o: thread -> (b = t>>5, o = t&31)
        const int bo = t >> 5, oo = t & 31;
        float lg = bl[bo * 32 + oo];
        if constexpr (IT == 2)
          lg += bbuf[(size_t)(b0 + bo) * (NI * NO) + (size_t)i * NO + oo];
        if constexpr (IT == 1)
          bbuf[(size_t)(b0 + bo) * (NI * NO) + (size_t)i * NO + oo] = lg;
        float mx = lg;
#pragma unroll
        for (int m = 1; m < 32; m <<= 1) mx = fmaxf(mx, __shfl_xor(mx, m));
        const float e = __expf(lg - mx);
        float sm = e;
#pragma unroll
        for (int m = 1; m < 32; m <<= 1) sm += __shfl_xor(sm, m);
        bl[bo * 32 + oo] = e / sm;
      }
      BARLDS();

#pragma unroll
      for (int j = 0; j < 4; ++j) {
        const float cj = bl[(l & 15) * 32 + w * 4 + j];
        sreg[2 * j]     += acc[2 * j]     * cj;
        sreg[2 * j + 1] += acc[2 * j + 1] * cj;
      }
    }
  }

  WAITV(0);   // drain redundant tail stages

  // flush partials, fragment-natural flat layout (coalesced float4)
  {
    float* op = spart + ((size_t)ib * NBB + bb) * 16384 + w * 2048 + l * 4;
#pragma unroll
    for (int tl = 0; tl < 8; ++tl) *(f32x4*)(op + tl * 256) = sreg[tl];
  }
}

// Reduce partials over i-blocks, emit s and per-block sumsq.
__global__ __launch_bounds__(256)
void caps_red(const float* __restrict__ spart, float* __restrict__ s,
              float* __restrict__ part)
{
  const int t = threadIdx.x;
  const size_t e = (size_t)blockIdx.x * 256 + t;
  float a = 0.f;
#pragma unroll
  for (int ibk = 0; ibk < NIB; ++ibk) a += spart[(size_t)ibk * (NBATCH * 1024) + e];
  s[e] = a;
  float qv = a * a;
#pragma unroll
  for (int m = 1; m < 64; m <<= 1) qv += __shfl_xor(qv, m);
  __shared__ float red[4];
  if ((t & 63) == 0) red[t >> 6] = qv;
  __syncthreads();
  if (t == 0) part[blockIdx.x] = red[0] + red[1] + red[2] + red[3];
}

__global__ __launch_bounds__(256)
void caps_norm(const float* __restrict__ part, float* __restrict__ fsc)
{
  const int t = threadIdx.x;
  float qv = part[t] + part[t + 256];
#pragma unroll
  for (int m = 1; m < 64; m <<= 1) qv += __shfl_xor(qv, m);
  __shared__ float red[4];
  if ((t & 63) == 0) red[t >> 6] = qv;
  __syncthreads();
  if (t == 0) {
    const float S = red[0] + red[1] + red[2] + red[3];
    fsc[0] = sqrtf(S) / (1.f + S);
  }
}

// Decode flat layout -> standard [b][od] output
__global__ __launch_bounds__(256)
void caps_out(const float* __restrict__ s, const float* __restrict__ fsc,
              float* __restrict__ out)
{
  const int E = blockIdx.x * 256 + threadIdx.x;
  const float v = s[E] * fsc[0];
  const int r = E & 3, ll = (E >> 2) & 63, tl = (E >> 8) & 7,
            w = (E >> 11) & 7, bb = E >> 14;
  const int b = bb * 16 + (ll & 15);
  const int od = w * 128 + tl * 16 + (ll >> 4) * 4 + r;
  out[b * 1024 + od] = v;
}

extern "C" void kernel_launch(void* const* d_in, const int* in_sizes, int n_in,
                              void* d_out, int out_size, void* d_ws, size_t ws_size,
                              hipStream_t stream)
{
  const float* xg = (const float*)d_in[0];
  const float* Wg = (const float*)d_in[1];
  float* out = (float*)d_out;

  // ws layout (floats): spart[32][131072] | s[131072] | part[512] | f[1] | bbuf
  float* wsf   = (float*)d_ws;
  float* spart = wsf;
  float* s     = spart + (size_t)NIB * NBATCH * 1024;
  float* part  = s + (size_t)NBATCH * 1024;
  float* fsc   = part + 512;
  float* bbuf  = fsc + 1;

  const int ldsB = LDS_FLOATS * 4;   // 130 KB dynamic LDS
  (void)hipFuncSetAttribute(reinterpret_cast<const void*>(&caps_pass<0>),
                            hipFuncAttributeMaxDynamicSharedMemorySize, ldsB);
  (void)hipFuncSetAttribute(reinterpret_cast<const void*>(&caps_pass<1>),
                            hipFuncAttributeMaxDynamicSharedMemorySize, ldsB);
  (void)hipFuncSetAttribute(reinterpret_cast<const void*>(&caps_pass<2>),
                            hipFuncAttributeMaxDynamicSharedMemorySize, ldsB);

  dim3 pg(NIB, NBB);   // (32, 8) = 256 blocks, 1/CU

  caps_pass<0><<<pg, 512, ldsB, stream>>>(xg, Wg, spart, s, fsc, bbuf);
  caps_red <<<512, 256, 0, stream>>>(spart, s, part);
  caps_norm<<<1,   256, 0, stream>>>(part, fsc);

  caps_pass<1><<<pg, 512, ldsB, stream>>>(xg, Wg, spart, s, fsc, bbuf);
  caps_red <<<512, 256, 0, stream>>>(spart, s, part);
  caps_norm<<<1,   256, 0, stream>>>(part, fsc);

  caps_pass<2><<<pg, 512, ldsB, stream>>>(xg, Wg, spart, s, fsc, bbuf);
  caps_red <<<512, 256, 0, stream>>>(spart, s, part);
  caps_norm<<<1,   256, 0, stream>>>(part, fsc);

  caps_out <<<512, 256, 0, stream>>>(s, fsc, out);
}